// Round 3
// baseline (282.501 us; speedup 1.0000x reference)
//
#include <hip/hip_runtime.h>
#include <math.h>

// 20-qubit, 4-layer hardware-efficient ansatz statevector sim. B=4, DIM=2^20.
// Qubit q <-> global index bit (19-q). Complex state stored as two float planes
// accessed via (pre, pim, STRD): interleaved-in-d_out (STRD=2, pim=pre+1) or
// split planes re=d_out / im=d_ws (STRD=1), chosen at runtime from out_size.
//
// Fusion: per layer per qubit U = RX(tx)*RZ(tz)*(H if layer 0) -> one butterfly.
// CNOT chain q=0..18 == gray gather out[y] = in[y ^ (y>>1)], split:
//   pass B: CX targets global bits 12..18 (controls 13..19, tile-local)
//   pass A: CX targets global bits 0..11 (controls 1..11 local, control 12 = tile bit)
// Per layer run B then A (matches reference gate order; cross-pass gates commute).
//
// Tiles: 4096 amps, 256 threads x 16 register amps.
//   pass A local bits = global 0..11 (contiguous tile), qubits 8..19
//   pass B local bits: 0..3 = global 0..3 (coalescing), 4..11 = global 12..19; qubits 0..7
// LDS 2x16KB; storage swizzle SW(j)=j^((j>>5)&31) applied at EVERY LDS write+read
// (logical slot maps stay un-swizzled so butterfly basis order is correct).

#define NQ 20

struct U2 { float r00,i00,r01,i01,r10,i10,r11,i11; };

__device__ __forceinline__ U2 make_u(const float* __restrict__ thx,
                                     const float* __restrict__ thz,
                                     int layer, int q, int withH) {
  float tx = 0.5f * thx[layer*NQ + q];
  float tz = 0.5f * thz[layer*NQ + q];
  float sx, cxv, sz, cz;
  sincosf(tx, &sx, &cxv);
  sincosf(tz, &sz, &cz);
  // U = RX*RZ: RX=[[c,-is],[-is,c]], RZ=diag(cz-isz, cz+isz)
  U2 u;
  u.r00 =  cxv*cz;  u.i00 = -cxv*sz;
  u.r01 =  sx*sz;   u.i01 = -sx*cz;
  u.r10 = -sx*sz;   u.i10 = -sx*cz;
  u.r11 =  cxv*cz;  u.i11 =  cxv*sz;
  if (withH) {  // U <- U*H (H hits the state first)
    const float r = 0.70710678118654752f;
    float a, b;
    a=u.r00; b=u.r01; u.r00=(a+b)*r; u.r01=(a-b)*r;
    a=u.i00; b=u.i01; u.i00=(a+b)*r; u.i01=(a-b)*r;
    a=u.r10; b=u.r11; u.r10=(a+b)*r; u.r11=(a-b)*r;
    a=u.i10; b=u.i11; u.i10=(a+b)*r; u.i11=(a-b)*r;
  }
  return u;
}

template <int ST>
__device__ __forceinline__ void bfly(float* re, float* im, const U2 u) {
#pragma unroll
  for (int s = 0; s < 16; ++s) {
    if ((s & ST) == 0) {
      const int s1 = s + ST;
      float ar = re[s], ai = im[s], br = re[s1], bi = im[s1];
      re[s]  = u.r00*ar - u.i00*ai + u.r01*br - u.i01*bi;
      im[s]  = u.r00*ai + u.i00*ar + u.r01*bi + u.i01*br;
      re[s1] = u.r10*ar - u.i10*ai + u.r11*br - u.i11*bi;
      im[s1] = u.r10*ai + u.i10*ar + u.r11*bi + u.i11*br;
    }
  }
}

__device__ __forceinline__ int SW(int j) { return j ^ ((j >> 5) & 31); }

// -------- pass B tail: butterflies qubits 0..7 + CX targets (global) 12..18 --------
// On entry: re/im hold M1 slots, slot s <-> local bits 8..11 (= global 16..19).
template <int STRD>
__device__ __forceinline__ void pass_b_tail(
    float* re, float* im, float* sre, float* sim,
    float* __restrict__ pre, float* __restrict__ pim,
    size_t base, int m, int t,
    const float* __restrict__ thx, const float* __restrict__ thz,
    int layer, int withH) {
  // M1 reg bits = local 8..11 -> qubits 3,2,1,0
  bfly<1>(re, im, make_u(thx, thz, layer, 3, withH));
  bfly<2>(re, im, make_u(thx, thz, layer, 2, withH));
  bfly<4>(re, im, make_u(thx, thz, layer, 1, withH));
  bfly<8>(re, im, make_u(thx, thz, layer, 0, withH));

#pragma unroll
  for (int s = 0; s < 16; ++s) { int k = SW((s << 8) | t); sre[k] = re[s]; sim[k] = im[s]; }
  __syncthreads();

  // M2: slot s <-> local bits 4..7 (= global 12..15) -> qubits 7,6,5,4
  const int th = t >> 4, tl = t & 15;
#pragma unroll
  for (int s = 0; s < 16; ++s) {
    int k = SW((th << 8) | (s << 4) | tl);
    re[s] = sre[k]; im[s] = sim[k];
  }
  bfly<1>(re, im, make_u(thx, thz, layer, 7, withH));
  bfly<2>(re, im, make_u(thx, thz, layer, 6, withH));
  bfly<4>(re, im, make_u(thx, thz, layer, 5, withH));
  bfly<8>(re, im, make_u(thx, thz, layer, 4, withH));
#pragma unroll
  for (int s = 0; s < 16; ++s) {     // write back own cells (1 owner per cell)
    int k = SW((th << 8) | (s << 4) | tl);
    sre[k] = re[s]; sim[k] = im[s];
  }
  __syncthreads();

  // CX gather (flip local bits 4..10 from bits 5..11) + store
#pragma unroll
  for (int s = 0; s < 16; ++s) {
    int y = (s << 8) | t;
    int x = y ^ ((y >> 1) & 0x7F0);
    int k = SW(x);
    int g = ((y >> 4) << 12) | (m << 4) | (y & 15);
    size_t o = (base + (size_t)g) * STRD;
    pre[o] = sre[k]; pim[o] = sim[k];
  }
}

template <int STRD>
__global__ __launch_bounds__(256) void pass_b_init(
    const float* __restrict__ in_re, const float* __restrict__ in_im,
    float* __restrict__ pre, float* __restrict__ pim,
    const float* __restrict__ thx, const float* __restrict__ thz) {
  __shared__ float sre[4096];
  __shared__ float sim[4096];
  const int t = threadIdx.x;
  const int b = blockIdx.x >> 8;
  const int m = blockIdx.x & 255;
  const size_t base = ((size_t)b) << NQ;
  float re[16], im[16];
#pragma unroll
  for (int s = 0; s < 16; ++s) {
    int j = (s << 8) | t;
    int g = ((j >> 4) << 12) | (m << 4) | (j & 15);
    re[s] = in_re[base + g]; im[s] = in_im[base + g];
  }
  pass_b_tail<STRD>(re, im, sre, sim, pre, pim, base, m, t, thx, thz, 0, 1);
}

template <int STRD>
__global__ __launch_bounds__(256) void pass_b_mid(
    float* __restrict__ pre, float* __restrict__ pim,
    const float* __restrict__ thx, const float* __restrict__ thz, int layer) {
  __shared__ float sre[4096];
  __shared__ float sim[4096];
  const int t = threadIdx.x;
  const int b = blockIdx.x >> 8;
  const int m = blockIdx.x & 255;
  const size_t base = ((size_t)b) << NQ;
  float re[16], im[16];
#pragma unroll
  for (int s = 0; s < 16; ++s) {
    int j = (s << 8) | t;
    int g = ((j >> 4) << 12) | (m << 4) | (j & 15);
    size_t o = (base + (size_t)g) * STRD;
    re[s] = pre[o]; im[s] = pim[o];
  }
  pass_b_tail<STRD>(re, im, sre, sim, pre, pim, base, m, t, thx, thz, layer, 0);
}

// -------- pass A: contiguous tile (global bits 0..11), qubits 8..19 + CX 0..11 -----
template <int STRD>
__global__ __launch_bounds__(256) void pass_a(
    float* __restrict__ pre, float* __restrict__ pim,
    const float* __restrict__ thx, const float* __restrict__ thz,
    int layer, int withH) {
  __shared__ float sre[4096];
  __shared__ float sim[4096];
  const int t = threadIdx.x;
  const int b = blockIdx.x >> 8;
  const int m = blockIdx.x & 255;
  const size_t base = (((size_t)b) << NQ) | ((size_t)m << 12);
  float re[16], im[16];

  // M1: slot s <-> local bits 8..11 -> qubits 11,10,9,8
#pragma unroll
  for (int s = 0; s < 16; ++s) {
    size_t o = (base + (size_t)((s << 8) | t)) * STRD;
    re[s] = pre[o]; im[s] = pim[o];
  }
  bfly<1>(re, im, make_u(thx, thz, layer, 11, withH));
  bfly<2>(re, im, make_u(thx, thz, layer, 10, withH));
  bfly<4>(re, im, make_u(thx, thz, layer,  9, withH));
  bfly<8>(re, im, make_u(thx, thz, layer,  8, withH));

#pragma unroll
  for (int s = 0; s < 16; ++s) { int k = SW((s << 8) | t); sre[k] = re[s]; sim[k] = im[s]; }
  __syncthreads();

  // M2: slot s <-> local bits 0..3 -> qubits 19,18,17,16
#pragma unroll
  for (int s = 0; s < 16; ++s) {
    int k = SW((t << 4) | s);
    re[s] = sre[k]; im[s] = sim[k];
  }
  bfly<1>(re, im, make_u(thx, thz, layer, 19, withH));
  bfly<2>(re, im, make_u(thx, thz, layer, 18, withH));
  bfly<4>(re, im, make_u(thx, thz, layer, 17, withH));
  bfly<8>(re, im, make_u(thx, thz, layer, 16, withH));
#pragma unroll
  for (int s = 0; s < 16; ++s) {
    int k = SW((t << 4) | s);
    sre[k] = re[s]; sim[k] = im[s];
  }
  __syncthreads();

  // M3: slot s <-> local bits 4..7 -> qubits 15,14,13,12
  const int th = t >> 4, tl = t & 15;
#pragma unroll
  for (int s = 0; s < 16; ++s) {
    int k = SW((th << 8) | (s << 4) | tl);
    re[s] = sre[k]; im[s] = sim[k];
  }
  bfly<1>(re, im, make_u(thx, thz, layer, 15, withH));
  bfly<2>(re, im, make_u(thx, thz, layer, 14, withH));
  bfly<4>(re, im, make_u(thx, thz, layer, 13, withH));
  bfly<8>(re, im, make_u(thx, thz, layer, 12, withH));
#pragma unroll
  for (int s = 0; s < 16; ++s) {
    int k = SW((th << 8) | (s << 4) | tl);
    sre[k] = re[s]; sim[k] = im[s];
  }
  __syncthreads();

  // CX gather: flip local bits 0..10 from bits 1..11; flip bit 11 from tile bit 12
  const int c11 = (m & 1) << 11;
#pragma unroll
  for (int s = 0; s < 16; ++s) {
    int y = (s << 8) | t;
    int x = y ^ ((y >> 1) & 0x7FF) ^ c11;
    int k = SW(x);
    size_t o = (base + (size_t)y) * STRD;
    pre[o] = sre[k]; pim[o] = sim[k];
  }
}

extern "C" void kernel_launch(void* const* d_in, const int* in_sizes, int n_in,
                              void* d_out, int out_size, void* d_ws, size_t ws_size,
                              hipStream_t stream) {
  const float* p_re = (const float*)d_in[0];
  const float* p_im = (const float*)d_in[1];
  const float* thx  = (const float*)d_in[2];
  const float* thz  = (const float*)d_in[3];

  dim3 grid(1024), blk(256);  // 4 batches x 256 tiles
  const long long FULL = 8LL << 20;  // 2 * B * DIM floats (interleaved complex)

  if ((long long)out_size >= FULL) {
    // complex64 interleaved in d_out: re at even floats, im at odd
    float* pre = (float*)d_out;
    float* pim = pre + 1;
    pass_b_init<2><<<grid, blk, 0, stream>>>(p_re, p_im, pre, pim, thx, thz);
    pass_a<2>    <<<grid, blk, 0, stream>>>(pre, pim, thx, thz, 0, 1);
    for (int l = 1; l < 4; ++l) {
      pass_b_mid<2><<<grid, blk, 0, stream>>>(pre, pim, thx, thz, l);
      pass_a<2>    <<<grid, blk, 0, stream>>>(pre, pim, thx, thz, l, 0);
    }
  } else {
    // split planes: real plane = d_out (the graded output), imag plane = d_ws
    float* pre = (float*)d_out;
    float* pim = (float*)d_ws;
    pass_b_init<1><<<grid, blk, 0, stream>>>(p_re, p_im, pre, pim, thx, thz);
    pass_a<1>    <<<grid, blk, 0, stream>>>(pre, pim, thx, thz, 0, 1);
    for (int l = 1; l < 4; ++l) {
      pass_b_mid<1><<<grid, blk, 0, stream>>>(pre, pim, thx, thz, l);
      pass_a<1>    <<<grid, blk, 0, stream>>>(pre, pim, thx, thz, l, 0);
    }
  }
}

// Round 6
// 248.129 us; speedup vs baseline: 1.1385x; 1.1385x over previous
//
#include <hip/hip_runtime.h>
#include <math.h>

// 20-qubit, 4-layer hardware-efficient ansatz statevector sim. B=4, DIM=2^20.
// Qubit q <-> global index bit (19-q). Complex state stored as two float planes
// accessed via (pre, pim, STRD): interleaved-in-d_out (STRD=2, pim=pre+1) or
// split planes re=d_out / im=d_ws (STRD=1), chosen at runtime from out_size.
//
// EXACT structure of the round-3 PASSING kernel; single change: library
// sincosf -> native __sinf/__cosf (v_sin_f32/v_cos_f32), uniform in all
// threads, to cut the per-thread transcendental cost ~25x.
//
// Fusion: per layer per qubit U = RX(tx)*RZ(tz)*(H if layer 0) -> one butterfly.
// CNOT chain q=0..18 == gray gather out[y] = in[y ^ (y>>1)], split:
//   pass B: CX targets global bits 12..18 (controls 13..19, tile-local)
//   pass A: CX targets global bits 0..11 (controls 1..11 local, control 12 = tile bit)
// Per layer run B then A (matches reference gate order; cross-pass gates commute).
//
// Tiles: 4096 amps, 256 threads x 16 register amps.
//   pass A local bits = global 0..11 (contiguous tile), qubits 8..19
//   pass B local bits: 0..3 = global 0..3 (coalescing), 4..11 = global 12..19; qubits 0..7
// LDS 2x16KB; storage swizzle SW(j)=j^((j>>5)&31) applied at EVERY LDS write+read
// (logical slot maps stay un-swizzled so butterfly basis order is correct).

#define NQ 20

struct U2 { float r00,i00,r01,i01,r10,i10,r11,i11; };

__device__ __forceinline__ U2 make_u(const float* __restrict__ thx,
                                     const float* __restrict__ thz,
                                     int layer, int q, int withH) {
  float tx = 0.5f * thx[layer*NQ + q];
  float tz = 0.5f * thz[layer*NQ + q];
  float sx  = __sinf(tx), cxv = __cosf(tx);
  float sz  = __sinf(tz), cz  = __cosf(tz);
  // U = RX*RZ: RX=[[c,-is],[-is,c]], RZ=diag(cz-isz, cz+isz)
  U2 u;
  u.r00 =  cxv*cz;  u.i00 = -cxv*sz;
  u.r01 =  sx*sz;   u.i01 = -sx*cz;
  u.r10 = -sx*sz;   u.i10 = -sx*cz;
  u.r11 =  cxv*cz;  u.i11 =  cxv*sz;
  if (withH) {  // U <- U*H (H hits the state first)
    const float r = 0.70710678118654752f;
    float a, b;
    a=u.r00; b=u.r01; u.r00=(a+b)*r; u.r01=(a-b)*r;
    a=u.i00; b=u.i01; u.i00=(a+b)*r; u.i01=(a-b)*r;
    a=u.r10; b=u.r11; u.r10=(a+b)*r; u.r11=(a-b)*r;
    a=u.i10; b=u.i11; u.i10=(a+b)*r; u.i11=(a-b)*r;
  }
  return u;
}

template <int ST>
__device__ __forceinline__ void bfly(float* re, float* im, const U2 u) {
#pragma unroll
  for (int s = 0; s < 16; ++s) {
    if ((s & ST) == 0) {
      const int s1 = s + ST;
      float ar = re[s], ai = im[s], br = re[s1], bi = im[s1];
      re[s]  = u.r00*ar - u.i00*ai + u.r01*br - u.i01*bi;
      im[s]  = u.r00*ai + u.i00*ar + u.r01*bi + u.i01*br;
      re[s1] = u.r10*ar - u.i10*ai + u.r11*br - u.i11*bi;
      im[s1] = u.r10*ai + u.i10*ar + u.r11*bi + u.i11*br;
    }
  }
}

__device__ __forceinline__ int SW(int j) { return j ^ ((j >> 5) & 31); }

// -------- pass B tail: butterflies qubits 0..7 + CX targets (global) 12..18 --------
// On entry: re/im hold M1 slots, slot s <-> local bits 8..11 (= global 16..19).
template <int STRD>
__device__ __forceinline__ void pass_b_tail(
    float* re, float* im, float* sre, float* sim,
    float* __restrict__ pre, float* __restrict__ pim,
    size_t base, int m, int t,
    const float* __restrict__ thx, const float* __restrict__ thz,
    int layer, int withH) {
  // M1 reg bits = local 8..11 -> qubits 3,2,1,0
  bfly<1>(re, im, make_u(thx, thz, layer, 3, withH));
  bfly<2>(re, im, make_u(thx, thz, layer, 2, withH));
  bfly<4>(re, im, make_u(thx, thz, layer, 1, withH));
  bfly<8>(re, im, make_u(thx, thz, layer, 0, withH));

#pragma unroll
  for (int s = 0; s < 16; ++s) { int k = SW((s << 8) | t); sre[k] = re[s]; sim[k] = im[s]; }
  __syncthreads();

  // M2: slot s <-> local bits 4..7 (= global 12..15) -> qubits 7,6,5,4
  const int th = t >> 4, tl = t & 15;
#pragma unroll
  for (int s = 0; s < 16; ++s) {
    int k = SW((th << 8) | (s << 4) | tl);
    re[s] = sre[k]; im[s] = sim[k];
  }
  bfly<1>(re, im, make_u(thx, thz, layer, 7, withH));
  bfly<2>(re, im, make_u(thx, thz, layer, 6, withH));
  bfly<4>(re, im, make_u(thx, thz, layer, 5, withH));
  bfly<8>(re, im, make_u(thx, thz, layer, 4, withH));
#pragma unroll
  for (int s = 0; s < 16; ++s) {     // write back own cells (1 owner per cell)
    int k = SW((th << 8) | (s << 4) | tl);
    sre[k] = re[s]; sim[k] = im[s];
  }
  __syncthreads();

  // CX gather (flip local bits 4..10 from bits 5..11) + store
#pragma unroll
  for (int s = 0; s < 16; ++s) {
    int y = (s << 8) | t;
    int x = y ^ ((y >> 1) & 0x7F0);
    int k = SW(x);
    int g = ((y >> 4) << 12) | (m << 4) | (y & 15);
    size_t o = (base + (size_t)g) * STRD;
    pre[o] = sre[k]; pim[o] = sim[k];
  }
}

template <int STRD>
__global__ __launch_bounds__(256) void pass_b_init(
    const float* __restrict__ in_re, const float* __restrict__ in_im,
    float* __restrict__ pre, float* __restrict__ pim,
    const float* __restrict__ thx, const float* __restrict__ thz) {
  __shared__ float sre[4096];
  __shared__ float sim[4096];
  const int t = threadIdx.x;
  const int b = blockIdx.x >> 8;
  const int m = blockIdx.x & 255;
  const size_t base = ((size_t)b) << NQ;
  float re[16], im[16];
#pragma unroll
  for (int s = 0; s < 16; ++s) {
    int j = (s << 8) | t;
    int g = ((j >> 4) << 12) | (m << 4) | (j & 15);
    re[s] = in_re[base + g]; im[s] = in_im[base + g];
  }
  pass_b_tail<STRD>(re, im, sre, sim, pre, pim, base, m, t, thx, thz, 0, 1);
}

template <int STRD>
__global__ __launch_bounds__(256) void pass_b_mid(
    float* __restrict__ pre, float* __restrict__ pim,
    const float* __restrict__ thx, const float* __restrict__ thz, int layer) {
  __shared__ float sre[4096];
  __shared__ float sim[4096];
  const int t = threadIdx.x;
  const int b = blockIdx.x >> 8;
  const int m = blockIdx.x & 255;
  const size_t base = ((size_t)b) << NQ;
  float re[16], im[16];
#pragma unroll
  for (int s = 0; s < 16; ++s) {
    int j = (s << 8) | t;
    int g = ((j >> 4) << 12) | (m << 4) | (j & 15);
    size_t o = (base + (size_t)g) * STRD;
    re[s] = pre[o]; im[s] = pim[o];
  }
  pass_b_tail<STRD>(re, im, sre, sim, pre, pim, base, m, t, thx, thz, layer, 0);
}

// -------- pass A: contiguous tile (global bits 0..11), qubits 8..19 + CX 0..11 -----
template <int STRD>
__global__ __launch_bounds__(256) void pass_a(
    float* __restrict__ pre, float* __restrict__ pim,
    const float* __restrict__ thx, const float* __restrict__ thz,
    int layer, int withH) {
  __shared__ float sre[4096];
  __shared__ float sim[4096];
  const int t = threadIdx.x;
  const int b = blockIdx.x >> 8;
  const int m = blockIdx.x & 255;
  const size_t base = (((size_t)b) << NQ) | ((size_t)m << 12);
  float re[16], im[16];

  // M1: slot s <-> local bits 8..11 -> qubits 11,10,9,8
#pragma unroll
  for (int s = 0; s < 16; ++s) {
    size_t o = (base + (size_t)((s << 8) | t)) * STRD;
    re[s] = pre[o]; im[s] = pim[o];
  }
  bfly<1>(re, im, make_u(thx, thz, layer, 11, withH));
  bfly<2>(re, im, make_u(thx, thz, layer, 10, withH));
  bfly<4>(re, im, make_u(thx, thz, layer,  9, withH));
  bfly<8>(re, im, make_u(thx, thz, layer,  8, withH));

#pragma unroll
  for (int s = 0; s < 16; ++s) { int k = SW((s << 8) | t); sre[k] = re[s]; sim[k] = im[s]; }
  __syncthreads();

  // M2: slot s <-> local bits 0..3 -> qubits 19,18,17,16
#pragma unroll
  for (int s = 0; s < 16; ++s) {
    int k = SW((t << 4) | s);
    re[s] = sre[k]; im[s] = sim[k];
  }
  bfly<1>(re, im, make_u(thx, thz, layer, 19, withH));
  bfly<2>(re, im, make_u(thx, thz, layer, 18, withH));
  bfly<4>(re, im, make_u(thx, thz, layer, 17, withH));
  bfly<8>(re, im, make_u(thx, thz, layer, 16, withH));
#pragma unroll
  for (int s = 0; s < 16; ++s) {
    int k = SW((t << 4) | s);
    sre[k] = re[s]; sim[k] = im[s];
  }
  __syncthreads();

  // M3: slot s <-> local bits 4..7 -> qubits 15,14,13,12
  const int th = t >> 4, tl = t & 15;
#pragma unroll
  for (int s = 0; s < 16; ++s) {
    int k = SW((th << 8) | (s << 4) | tl);
    re[s] = sre[k]; im[s] = sim[k];
  }
  bfly<1>(re, im, make_u(thx, thz, layer, 15, withH));
  bfly<2>(re, im, make_u(thx, thz, layer, 14, withH));
  bfly<4>(re, im, make_u(thx, thz, layer, 13, withH));
  bfly<8>(re, im, make_u(thx, thz, layer, 12, withH));
#pragma unroll
  for (int s = 0; s < 16; ++s) {
    int k = SW((th << 8) | (s << 4) | tl);
    sre[k] = re[s]; sim[k] = im[s];
  }
  __syncthreads();

  // CX gather: flip local bits 0..10 from bits 1..11; flip bit 11 from tile bit 12
  const int c11 = (m & 1) << 11;
#pragma unroll
  for (int s = 0; s < 16; ++s) {
    int y = (s << 8) | t;
    int x = y ^ ((y >> 1) & 0x7FF) ^ c11;
    int k = SW(x);
    size_t o = (base + (size_t)y) * STRD;
    pre[o] = sre[k]; pim[o] = sim[k];
  }
}

extern "C" void kernel_launch(void* const* d_in, const int* in_sizes, int n_in,
                              void* d_out, int out_size, void* d_ws, size_t ws_size,
                              hipStream_t stream) {
  const float* p_re = (const float*)d_in[0];
  const float* p_im = (const float*)d_in[1];
  const float* thx  = (const float*)d_in[2];
  const float* thz  = (const float*)d_in[3];

  dim3 grid(1024), blk(256);  // 4 batches x 256 tiles
  const long long FULL = 8LL << 20;  // 2 * B * DIM floats (interleaved complex)

  if ((long long)out_size >= FULL) {
    // complex64 interleaved in d_out: re at even floats, im at odd
    float* pre = (float*)d_out;
    float* pim = pre + 1;
    pass_b_init<2><<<grid, blk, 0, stream>>>(p_re, p_im, pre, pim, thx, thz);
    pass_a<2>    <<<grid, blk, 0, stream>>>(pre, pim, thx, thz, 0, 1);
    for (int l = 1; l < 4; ++l) {
      pass_b_mid<2><<<grid, blk, 0, stream>>>(pre, pim, thx, thz, l);
      pass_a<2>    <<<grid, blk, 0, stream>>>(pre, pim, thx, thz, l, 0);
    }
  } else {
    // split planes: real plane = d_out (the graded output), imag plane = d_ws
    float* pre = (float*)d_out;
    float* pim = (float*)d_ws;
    pass_b_init<1><<<grid, blk, 0, stream>>>(p_re, p_im, pre, pim, thx, thz);
    pass_a<1>    <<<grid, blk, 0, stream>>>(pre, pim, thx, thz, 0, 1);
    for (int l = 1; l < 4; ++l) {
      pass_b_mid<1><<<grid, blk, 0, stream>>>(pre, pim, thx, thz, l);
      pass_a<1>    <<<grid, blk, 0, stream>>>(pre, pim, thx, thz, l, 0);
    }
  }
}

// Round 8
// 236.675 us; speedup vs baseline: 1.1936x; 1.0484x over previous
//
#include <hip/hip_runtime.h>
#include <math.h>

// 20-qubit, 4-layer hardware-efficient ansatz statevector sim. B=4, DIM=2^20.
// Qubit q <-> global index bit (19-q).
//
// STATE LAYOUT (root cause of 5 aborted rounds): out_size = B*DIM = 4,194,304 —
// d_out holds ONLY the real plane (harness casts complex64 ref to float32).
// So: real plane = d_out, imag plane = d_ws (>=256MB), both [B, 2^20] contiguous.
// All global IO is float4 on these planes (4 consecutive amplitudes' re or im).
//
// Fusion: per layer per qubit U = RX(tx)*RZ(tz)*(H if layer 0), one butterfly.
// CNOT chain q=0..18 == gray gather out[y] = in[y ^ (y>>1)], split:
//   pass B: CX targets global bits 12..18 (controls 13..19, tile-local)
//   pass A: CX targets global bits 0..11 (controls 1..11 local, control 12 = tile bit)
// Per layer: B then A (matches reference gate order; cross-pass gates commute).
//
// Tiles: 4096 amps, 256 threads x 16 register slots, 3 LDS phases per pass.
//   pass A local j = global bits 0..11 (contiguous tile); qubits 8..19
//     M1 reg = j{0,1,10,11} (q19,q18,q9,q8)  [float4 global load]
//     M2 reg = j{2,3,4,5}   (q17,q16,q15,q14)
//     M3 reg = j{6,7,8,9}   (q13,q12,q11,q10)
//     gather x=y^((y>>1)&0x7FF)^c11: 4-groups map to 4-groups with gray permute
//   pass B local j: bits 0..3 = global 0..3, bits 4..11 = global 12..19; qubits 0..7
//     M1 reg = j{0,1,10,11} (—,—,q1,q0)      [float4 global load]
//     M2 reg = j{4,5,6,7}   (q7,q6,q5,q4)
//     M3 reg = j{0,1,8,9}   (—,—,q3,q2)      [float4 LDS]
//     gather x=y^((y>>1)&0x7F0): bits 0..3 untouched -> direct float4 copy
// LDS: sre/sim float[4096] (32KB); swizzle K(j)=j^(((j>>6)&0xF)<<2) (bits 2..5
// ^= bits 6..9; preserves bits 0,1 so float4 groups stay aligned). All scalar
// patterns <=2-way banked (free); all b128 patterns at natural density.

#define NQ 20

struct U2 { float r00,i00,r01,i01,r10,i10,r11,i11; };

__device__ __forceinline__ U2 make_u(const float* __restrict__ thx,
                                     const float* __restrict__ thz,
                                     int layer, int q, int withH) {
  float tx = 0.5f * thx[layer*NQ + q];
  float tz = 0.5f * thz[layer*NQ + q];
  float sx  = __sinf(tx), cxv = __cosf(tx);
  float sz  = __sinf(tz), cz  = __cosf(tz);
  U2 u;
  u.r00 =  cxv*cz;  u.i00 = -cxv*sz;
  u.r01 =  sx*sz;   u.i01 = -sx*cz;
  u.r10 = -sx*sz;   u.i10 = -sx*cz;
  u.r11 =  cxv*cz;  u.i11 =  cxv*sz;
  if (withH) {
    const float r = 0.70710678118654752f;
    float a, b;
    a=u.r00; b=u.r01; u.r00=(a+b)*r; u.r01=(a-b)*r;
    a=u.i00; b=u.i01; u.i00=(a+b)*r; u.i01=(a-b)*r;
    a=u.r10; b=u.r11; u.r10=(a+b)*r; u.r11=(a-b)*r;
    a=u.i10; b=u.i11; u.i10=(a+b)*r; u.i11=(a-b)*r;
  }
  return u;
}

template <int ST>
__device__ __forceinline__ void bfly(float* re, float* im, const U2 u) {
#pragma unroll
  for (int s = 0; s < 16; ++s) {
    if ((s & ST) == 0) {
      const int s1 = s + ST;
      float ar = re[s], ai = im[s], br = re[s1], bi = im[s1];
      re[s]  = u.r00*ar - u.i00*ai + u.r01*br - u.i01*bi;
      im[s]  = u.r00*ai + u.i00*ar + u.r01*bi + u.i01*br;
      re[s1] = u.r10*ar - u.i10*ai + u.r11*br - u.i11*bi;
      im[s1] = u.r10*ai + u.i10*ar + u.r11*bi + u.i11*br;
    }
  }
}

__device__ __forceinline__ int K(int j) { return j ^ (((j >> 6) & 0xF) << 2); }

// -------- pass A: tile = global bits 0..11 contiguous; qubits 8..19 + CX 0..11 -----
__global__ __launch_bounds__(256) void pass_a(
    float* __restrict__ pre, float* __restrict__ pim,
    const float* __restrict__ thx, const float* __restrict__ thz,
    int layer, int withH) {
  __shared__ __align__(16) float sre[4096];
  __shared__ __align__(16) float sim[4096];
  float4* sre4 = (float4*)sre;
  float4* sim4 = (float4*)sim;
  const int t = threadIdx.x;
  const int b = blockIdx.x >> 8;
  const int m = blockIdx.x & 255;
  const size_t base = (((size_t)b) << NQ) | ((size_t)m << 12);
  float4* pr4 = (float4*)(pre + base);
  float4* pi4 = (float4*)(pim + base);
  float re[16], im[16];

  // M1: slot s=(hi<<2)|e; j=(hi<<10)|(t<<2)|e
#pragma unroll
  for (int hi = 0; hi < 4; ++hi) {
    float4 vr = pr4[(hi << 8) | t];
    float4 vi = pi4[(hi << 8) | t];
    re[4*hi+0]=vr.x; re[4*hi+1]=vr.y; re[4*hi+2]=vr.z; re[4*hi+3]=vr.w;
    im[4*hi+0]=vi.x; im[4*hi+1]=vi.y; im[4*hi+2]=vi.z; im[4*hi+3]=vi.w;
  }
  bfly<1>(re, im, make_u(thx, thz, layer, 19, withH));  // j0
  bfly<2>(re, im, make_u(thx, thz, layer, 18, withH));  // j1
  bfly<4>(re, im, make_u(thx, thz, layer,  9, withH));  // j10
  bfly<8>(re, im, make_u(thx, thz, layer,  8, withH));  // j11

#pragma unroll
  for (int hi = 0; hi < 4; ++hi) {
    int F = K((hi << 10) | (t << 2)) >> 2;
    sre4[F] = make_float4(re[4*hi+0], re[4*hi+1], re[4*hi+2], re[4*hi+3]);
    sim4[F] = make_float4(im[4*hi+0], im[4*hi+1], im[4*hi+2], im[4*hi+3]);
  }
  __syncthreads();

  // M2: reg = j bits 2..5; thread bits {0,1,6..11}
  const int jt2 = (t & 3) | ((t & 0xFC) << 4);
#pragma unroll
  for (int s = 0; s < 16; ++s) {
    int k = K(jt2 | (s << 2));
    re[s] = sre[k]; im[s] = sim[k];
  }
  bfly<1>(re, im, make_u(thx, thz, layer, 17, withH));  // j2
  bfly<2>(re, im, make_u(thx, thz, layer, 16, withH));  // j3
  bfly<4>(re, im, make_u(thx, thz, layer, 15, withH));  // j4
  bfly<8>(re, im, make_u(thx, thz, layer, 14, withH));  // j5
#pragma unroll
  for (int s = 0; s < 16; ++s) {  // own cells
    int k = K(jt2 | (s << 2));
    sre[k] = re[s]; sim[k] = im[s];
  }
  __syncthreads();

  // M3: reg = j bits 6..9; thread bits {0..5,10,11}
  const int jt3 = (t & 63) | ((t & 0xC0) << 4);
#pragma unroll
  for (int s = 0; s < 16; ++s) {
    int k = K(jt3 | (s << 6));
    re[s] = sre[k]; im[s] = sim[k];
  }
  bfly<1>(re, im, make_u(thx, thz, layer, 13, withH));  // j6
  bfly<2>(re, im, make_u(thx, thz, layer, 12, withH));  // j7
  bfly<4>(re, im, make_u(thx, thz, layer, 11, withH));  // j8
  bfly<8>(re, im, make_u(thx, thz, layer, 10, withH));  // j9
#pragma unroll
  for (int s = 0; s < 16; ++s) {  // own cells
    int k = K(jt3 | (s << 6));
    sre[k] = re[s]; sim[k] = im[s];
  }
  __syncthreads();

  // CX gather: x = y ^ ((y>>1)&0x7FF) ^ c11.
  // 4-group {y0..y0+3} sources = aligned group (x0&~3), element sel = (x0&3)^gray(e).
  const int c11 = (m & 1) << 11;
#pragma unroll
  for (int hi = 0; hi < 4; ++hi) {
    int y0 = (hi << 10) | (t << 2);
    int x0 = y0 ^ ((y0 >> 1) & 0x7FF) ^ c11;   // bit0 always 0
    int FG = K(x0 & ~3) >> 2;
    float4 vr = sre4[FG], vi = sim4[FG];
    if (x0 & 2) {
      vr = make_float4(vr.z, vr.w, vr.x, vr.y);
      vi = make_float4(vi.z, vi.w, vi.x, vi.y);
    }
    pr4[(hi << 8) | t] = make_float4(vr.x, vr.y, vr.w, vr.z);  // gray: e=2<->3 swap
    pi4[(hi << 8) | t] = make_float4(vi.x, vi.y, vi.w, vi.z);
  }
}

// -------- pass B: local j0..3 = global 0..3, j4..11 = global 12..19 ---------------
// tile m = global bits 4..11; butterflies qubits 0..7 + CX targets global 12..18
__global__ __launch_bounds__(256) void pass_b(
    const float* __restrict__ src_re, const float* __restrict__ src_im,
    float* __restrict__ pre, float* __restrict__ pim,
    const float* __restrict__ thx, const float* __restrict__ thz,
    int layer, int withH) {
  __shared__ __align__(16) float sre[4096];
  __shared__ __align__(16) float sim[4096];
  float4* sre4 = (float4*)sre;
  float4* sim4 = (float4*)sim;
  const int t = threadIdx.x;
  const int b = blockIdx.x >> 8;
  const int m = blockIdx.x & 255;
  const size_t base = ((size_t)b) << NQ;
  float re[16], im[16];

  // M1: slot s=(hi<<2)|e; j=(hi<<10)|(t<<2)|e; g=((j>>4)<<12)|(m<<4)|(j&15)
#pragma unroll
  for (int hi = 0; hi < 4; ++hi) {
    int j0 = (hi << 10) | (t << 2);
    int g0 = ((j0 >> 4) << 12) | (m << 4) | (j0 & 15);
    float4 vr = *(const float4*)(src_re + base + g0);
    float4 vi = *(const float4*)(src_im + base + g0);
    re[4*hi+0]=vr.x; re[4*hi+1]=vr.y; re[4*hi+2]=vr.z; re[4*hi+3]=vr.w;
    im[4*hi+0]=vi.x; im[4*hi+1]=vi.y; im[4*hi+2]=vi.z; im[4*hi+3]=vi.w;
  }
  bfly<4>(re, im, make_u(thx, thz, layer, 1, withH));   // j10 (global 18)
  bfly<8>(re, im, make_u(thx, thz, layer, 0, withH));   // j11 (global 19)

#pragma unroll
  for (int hi = 0; hi < 4; ++hi) {
    int F = K((hi << 10) | (t << 2)) >> 2;
    sre4[F] = make_float4(re[4*hi+0], re[4*hi+1], re[4*hi+2], re[4*hi+3]);
    sim4[F] = make_float4(im[4*hi+0], im[4*hi+1], im[4*hi+2], im[4*hi+3]);
  }
  __syncthreads();

  // M2: reg = j bits 4..7 (global 12..15); thread bits {0..3,8..11}
  const int jt2 = (t & 15) | ((t & 0xF0) << 4);
#pragma unroll
  for (int s = 0; s < 16; ++s) {
    int k = K(jt2 | (s << 4));
    re[s] = sre[k]; im[s] = sim[k];
  }
  bfly<1>(re, im, make_u(thx, thz, layer, 7, withH));   // j4
  bfly<2>(re, im, make_u(thx, thz, layer, 6, withH));   // j5
  bfly<4>(re, im, make_u(thx, thz, layer, 5, withH));   // j6
  bfly<8>(re, im, make_u(thx, thz, layer, 4, withH));   // j7
#pragma unroll
  for (int s = 0; s < 16; ++s) {  // own cells
    int k = K(jt2 | (s << 4));
    sre[k] = re[s]; sim[k] = im[s];
  }
  __syncthreads();

  // M3: reg = j bits {0,1,8,9}; thread bits {2..7,10,11}; float4 LDS groups
  const int jt3 = ((t & 63) << 2) | ((t & 0xC0) << 4);
#pragma unroll
  for (int sh = 0; sh < 4; ++sh) {
    int FG = K(jt3 | (sh << 8)) >> 2;
    float4 vr = sre4[FG], vi = sim4[FG];
    re[4*sh+0]=vr.x; re[4*sh+1]=vr.y; re[4*sh+2]=vr.z; re[4*sh+3]=vr.w;
    im[4*sh+0]=vi.x; im[4*sh+1]=vi.y; im[4*sh+2]=vi.z; im[4*sh+3]=vi.w;
  }
  bfly<4>(re, im, make_u(thx, thz, layer, 3, withH));   // j8 (global 16)
  bfly<8>(re, im, make_u(thx, thz, layer, 2, withH));   // j9 (global 17)
#pragma unroll
  for (int sh = 0; sh < 4; ++sh) {  // own groups
    int FG = K(jt3 | (sh << 8)) >> 2;
    sre4[FG] = make_float4(re[4*sh+0], re[4*sh+1], re[4*sh+2], re[4*sh+3]);
    sim4[FG] = make_float4(im[4*sh+0], im[4*sh+1], im[4*sh+2], im[4*sh+3]);
  }
  __syncthreads();

  // CX gather: x = y ^ ((y>>1)&0x7F0) — bits 0..3 untouched, direct float4 copy
#pragma unroll
  for (int hi = 0; hi < 4; ++hi) {
    int y0 = (hi << 10) | (t << 2);
    int x0 = y0 ^ ((y0 >> 1) & 0x7F0);       // 4-aligned
    int FG = K(x0) >> 2;
    float4 vr = sre4[FG], vi = sim4[FG];
    int g0 = ((y0 >> 4) << 12) | (m << 4) | (y0 & 15);
    *(float4*)(pre + base + g0) = vr;
    *(float4*)(pim + base + g0) = vi;
  }
}

extern "C" void kernel_launch(void* const* d_in, const int* in_sizes, int n_in,
                              void* d_out, int out_size, void* d_ws, size_t ws_size,
                              hipStream_t stream) {
  const float* p_re = (const float*)d_in[0];
  const float* p_im = (const float*)d_in[1];
  const float* thx  = (const float*)d_in[2];
  const float* thz  = (const float*)d_in[3];
  float* pre = (float*)d_out;   // real plane  [B, 2^20] — the graded output
  float* pim = (float*)d_ws;    // imag plane  [B, 2^20] in workspace

  dim3 grid(1024), blk(256);    // 4 batches x 256 tiles
  pass_b<<<grid, blk, 0, stream>>>(p_re, p_im, pre, pim, thx, thz, 0, 1);
  pass_a<<<grid, blk, 0, stream>>>(pre, pim, thx, thz, 0, 1);
  for (int l = 1; l < 4; ++l) {
    pass_b<<<grid, blk, 0, stream>>>(pre, pim, pre, pim, thx, thz, l, 0);
    pass_a<<<grid, blk, 0, stream>>>(pre, pim, thx, thz, l, 0);
  }
}